// Round 3
// baseline (1045.330 us; speedup 1.0000x reference)
//
#include <hip/hip_runtime.h>

// GATRNN: T=12 steps of {GAT1(inputs_t) -> GRU -> GAT2}, then Linear(H->D).
// fp32 I/O. Graph hardcoded: edge k: sender=k/63, receiver=k%63; node 63 inert.
// R3: parallel-softmax attention (32-lane subgroup per receiver) + persistent
// single-dispatch T-loop with agent-scope grid barrier (256 blocks, 1/CU).

#define T_   12
#define B_   32
#define N_   64
#define D_   2
#define H_   128
#define HID_ 32
#define HEAD_ 4
#define NA_  63
#define NBLK_ 256

__device__ __forceinline__ float eluf(float x){ return x>0.f ? x : expm1f(x); }
__device__ __forceinline__ void load8(const float4* p, int ch, float* f){
  float4 a = p[2*ch], b = p[2*ch+1];
  f[0]=a.x; f[1]=a.y; f[2]=a.z; f[3]=a.w; f[4]=b.x; f[5]=b.y; f[6]=b.z; f[7]=b.w;
}

// ---- ws layout (floats) ----
#define OFF_H    0u
#define OFF_X1   262144u          // T*B*N*HID = 786432
#define OFF_PS1  1048576u         // T*B*N*HEAD = 98304
#define OFF_PR1  1146880u
#define OFF_XG   1245184u         // T*B*N*H = 3145728
#define OFF_X2   4390912u         // B*N*HID = 65536
#define OFF_PS2  4456448u         // B*N*HEAD = 8192
#define OFF_PR2  4464640u         // + 8192
#define OFF_BAR  4472832u         // 16 uints (memset to 0 each launch)

// ---------------- grid barrier (agent scope) ----------------
__device__ __forceinline__ void gbar(unsigned* cnt, unsigned target){
  __syncthreads();
  if(threadIdx.x == 0){
    __hip_atomic_fetch_add(cnt, 1u, __ATOMIC_ACQ_REL, __HIP_MEMORY_SCOPE_AGENT);
    while(__hip_atomic_load(cnt, __ATOMIC_ACQUIRE, __HIP_MEMORY_SCOPE_AGENT) < target){
      __builtin_amdgcn_s_sleep(1);
    }
  }
  __syncthreads();
}

// ---------------- attention subgroup (32 lanes, one receiver) ----------------
// sx2: senders 63x32 (LDS), sps: 63x4 (LDS), se_sg: 256-float scratch (LDS),
// ss_sg: 4 floats (LDS). Wave-lockstep: no __syncthreads needed inside.
__device__ __forceinline__ void att_subgroup(
    const float* sx2, const float* sps, float* se_sg, float* ss_sg,
    float prj, int l, float* orow){
  int hh = l & 3, i0 = l >> 2;
  float pmax = -1e30f;
  #pragma unroll
  for(int k = 0; k < 8; k++){
    int i = i0 + 8*k;
    if(i < NA_){
      float v = eluf(sps[i*4 + hh] + prj);
      se_sg[i*4 + hh] = v;
      pmax = fmaxf(pmax, v);
    }
  }
  #pragma unroll
  for(int st = 4; st < 32; st <<= 1) pmax = fmaxf(pmax, __shfl_xor(pmax, st, 32));
  float psum = 0.f;
  #pragma unroll
  for(int k = 0; k < 8; k++){
    int i = i0 + 8*k;
    if(i < NA_){
      float e = expf(se_sg[i*4 + hh] - pmax);
      se_sg[i*4 + hh] = e;
      psum += e;
    }
  }
  #pragma unroll
  for(int st = 4; st < 32; st <<= 1) psum += __shfl_xor(psum, st, 32);
  if(i0 == 0) ss_sg[hh] = psum;
  float a0=0.f, a1=0.f, a2=0.f, a3=0.f;
  for(int i = 0; i < NA_; i++){
    float4 e4 = *(const float4*)&se_sg[i*4];
    float xv = sx2[i*32 + l];
    a0 += e4.x*xv; a1 += e4.y*xv; a2 += e4.z*xv; a3 += e4.w*xv;
  }
  orow[l]      = eluf(a0 / ss_sg[0]);
  orow[32 + l] = eluf(a1 / ss_sg[1]);
  orow[64 + l] = eluf(a2 / ss_sg[2]);
  orow[96 + l] = eluf(a3 / ss_sg[3]);
}

// GAT1 fc1 + edge projections for ALL t, grid = T*B, block 256.
__global__ void gat1_fc(const float* __restrict__ inp, const float* __restrict__ W1,
                        const float* __restrict__ b1, const float* __restrict__ W2,
                        const float* __restrict__ b2,
                        float* __restrict__ x1_all, float* __restrict__ ps_all,
                        float* __restrict__ pr_all){
  int grp = blockIdx.x;
  int tid = threadIdx.x;
  __shared__ float sx1[N_*HID_];
  __shared__ float sW1[HID_*D_];
  __shared__ float sb1[HID_];
  __shared__ float sW2[HEAD_*2*HID_];
  __shared__ float sxin[N_*D_];
  if(tid < 64)  sW1[tid] = W1[tid];
  if(tid < 32)  sb1[tid] = b1[tid];
  sW2[tid] = W2[tid];
  if(tid < 128) sxin[tid] = inp[grp*N_*D_ + tid];
  __syncthreads();
  for(int o = tid; o < N_*HID_; o += 256){
    int n = o >> 5, k = o & 31;
    float v = sb1[k] + sxin[n*2]*sW1[k*2] + sxin[n*2+1]*sW1[k*2+1];
    sx1[o] = v;
    x1_all[grp*N_*HID_ + o] = v;
  }
  __syncthreads();
  for(int p = tid; p < N_*8; p += 256){
    int n = p >> 3, q = p & 7, hh = q & 3;
    const float* w  = sW2 + hh*64 + ((q < 4) ? 0 : 32);
    const float* xr = sx1 + n*32;
    float acc = (q < 4) ? b2[hh] : 0.f;
    #pragma unroll
    for(int c = 0; c < 32; c++) acc += xr[c]*w[c];
    if(q < 4) ps_all[grp*N_*HEAD_ + n*4 + hh] = acc;
    else      pr_all[grp*N_*HEAD_ + n*4 + hh] = acc;
  }
}

// Parallel-softmax attention: 8 receivers per block (same grp). grid = G*8.
__global__ __launch_bounds__(256) void att8(const float* __restrict__ x1,
                                            const float* __restrict__ ps,
                                            const float* __restrict__ pr,
                                            float* __restrict__ out){
  __shared__ float smem[4384];
  float* sx2 = smem;            // 2016 (pad 2048)
  float* sps = smem + 2048;     // 252  (pad 256)
  float* se  = smem + 2304;     // 8*256
  float* ss  = smem + 4352;     // 8*4
  int blk = blockIdx.x, tid = threadIdx.x;
  int grp = blk >> 3;
  const float* x1g = x1 + (size_t)grp * (N_*HID_);
  const float* psg = ps + (size_t)grp * (N_*HEAD_);
  for(int i = tid; i < NA_*HID_; i += 256) sx2[i] = x1g[i];
  for(int i = tid; i < NA_*HEAD_; i += 256) sps[i] = psg[i];
  __syncthreads();
  int sg = tid >> 5, l = tid & 31;
  int idx = blk*8 + sg, j = idx & 63;
  float* orow = out + (size_t)idx * H_;
  if(j == NA_){
    #pragma unroll
    for(int q = 0; q < 4; q++) orow[q*32 + l] = 0.f;
    return;
  }
  float prj = pr[(size_t)idx*4 + (l & 3)];
  att_subgroup(sx2, sps, se + sg*256, ss + sg*4, prj, l, orow);
}

// Persistent T-loop: GRU (8 rows/block) -> barrier -> GAT2 attention
// (8 receivers/block) -> barrier, x12, then final Linear. grid 256 x 256.
__global__ __launch_bounds__(256, 1) void loop_k(
    const float* __restrict__ xg_all, const float* __restrict__ h0,
    const float* __restrict__ Wih, const float* __restrict__ Whh,
    const float* __restrict__ bih, const float* __restrict__ bhh,
    const float* __restrict__ W1, const float* __restrict__ b1,
    const float* __restrict__ W2, const float* __restrict__ b2,
    const float* __restrict__ oW, const float* __restrict__ ob,
    float* hbuf, float* x2, float* ps2, float* pr2,
    float* __restrict__ pred, unsigned* bar){
  __shared__ float smem[4384];
  int tid = threadIdx.x;
  int blk = blockIdx.x;
  int g0 = blk * 8;
  unsigned ep = 0;

  for(int t = 0; t < T_; t++){
    // ---------------- GRU + GAT2 fc1/fc2 for rows g0..g0+7 ----------------
    {
      float (*sx)[H_] = (float(*)[H_])smem;          // x_gat input, then h_gru
      float (*sh)[H_] = (float(*)[H_])(smem + 1024); // h_prev, then x2 tile
      const float* xg = xg_all + (size_t)t * (B_*N_*H_);
      const float* hsrc = (t == 0) ? h0 : hbuf;
      for(int i = tid; i < 8*H_; i += 256){
        ((float*)sx)[i] = xg[g0*H_ + i];
        ((float*)sh)[i] = hsrc[g0*H_ + i];
      }
      __syncthreads();

      int c = tid & 127, rg4 = (tid >> 7) * 4;
      const float4* w0 = (const float4*)(Wih + (size_t)c*H_);
      const float4* w1p= (const float4*)(Wih + (size_t)(c+H_)*H_);
      const float4* w2p= (const float4*)(Wih + (size_t)(c+2*H_)*H_);
      const float4* w3 = (const float4*)(Whh + (size_t)c*H_);
      const float4* w4 = (const float4*)(Whh + (size_t)(c+H_)*H_);
      const float4* w5 = (const float4*)(Whh + (size_t)(c+2*H_)*H_);
      float a0[4]={0,0,0,0}, a1[4]={0,0,0,0}, a2[4]={0,0,0,0};
      float a3[4]={0,0,0,0}, a4[4]={0,0,0,0}, a5[4]={0,0,0,0};
      #pragma unroll 2
      for(int ch = 0; ch < 16; ch++){
        float f0[8], f1[8], f2[8], f3[8], f4[8], f5[8];
        load8(w0, ch, f0); load8(w1p, ch, f1); load8(w2p, ch, f2);
        load8(w3, ch, f3); load8(w4, ch, f4); load8(w5, ch, f5);
        #pragma unroll
        for(int rr = 0; rr < 4; rr++){
          const float4 xa = *(const float4*)&sx[rg4+rr][ch*8];
          const float4 xb = *(const float4*)&sx[rg4+rr][ch*8+4];
          const float4 ha = *(const float4*)&sh[rg4+rr][ch*8];
          const float4 hb = *(const float4*)&sh[rg4+rr][ch*8+4];
          float xv[8] = {xa.x,xa.y,xa.z,xa.w,xb.x,xb.y,xb.z,xb.w};
          float hv[8] = {ha.x,ha.y,ha.z,ha.w,hb.x,hb.y,hb.z,hb.w};
          #pragma unroll
          for(int kk = 0; kk < 8; kk++){
            a0[rr] += f0[kk]*xv[kk]; a1[rr] += f1[kk]*xv[kk]; a2[rr] += f2[kk]*xv[kk];
            a3[rr] += f3[kk]*hv[kk]; a4[rr] += f4[kk]*hv[kk]; a5[rr] += f5[kk]*hv[kk];
          }
        }
      }
      float bir = bih[c], biz = bih[c+H_], bin = bih[c+2*H_];
      float bhr = bhh[c], bhz = bhh[c+H_], bhn = bhh[c+2*H_];
      float hnew[4];
      #pragma unroll
      for(int rr = 0; rr < 4; rr++){
        float ir = a0[rr]+bir, iz = a1[rr]+biz, in_ = a2[rr]+bin;
        float hr = a3[rr]+bhr, hz = a4[rr]+bhz, hn = a5[rr]+bhn;
        float r = 1.f/(1.f+expf(-(ir+hr)));
        float z = 1.f/(1.f+expf(-(iz+hz)));
        float n = tanhf(in_ + r*hn);
        hnew[rr] = (1.f-z)*n + z*sh[rg4+rr][c];
      }
      __syncthreads();
      #pragma unroll
      for(int rr = 0; rr < 4; rr++) sx[rg4+rr][c] = hnew[rr];  // sx := h_gru
      __syncthreads();

      // GAT2 fc1: 8 rows x 32 cols
      {
        int r = tid >> 5, jc = tid & 31;
        const float4* wr = (const float4*)(W1 + (size_t)jc*H_);
        float acc = b1[jc];
        #pragma unroll 4
        for(int ch = 0; ch < 16; ch++){
          float w[8]; load8(wr, ch, w);
          const float* hgr = &sx[r][ch*8];
          #pragma unroll
          for(int kk = 0; kk < 8; kk++) acc += w[kk]*hgr[kk];
        }
        sh[r][jc] = acc;
        x2[(size_t)(g0+r)*HID_ + jc] = acc;
      }
      __syncthreads();
      if(tid < 64){
        int r = tid >> 3, q = tid & 7, hh = q & 3;
        int base = (q < 4) ? 0 : 32;
        float acc = (q < 4) ? b2[hh] : 0.f;
        #pragma unroll
        for(int cc = 0; cc < 32; cc++) acc += sh[r][cc]*W2[hh*64 + base + cc];
        if(q < 4) ps2[(g0+r)*HEAD_ + hh] = acc;
        else      pr2[(g0+r)*HEAD_ + hh] = acc;
      }
    }
    gbar(bar, (++ep) * NBLK_);

    // ---------------- GAT2 attention for receivers g0..g0+7 ----------------
    {
      float* sx2 = smem;            // 2016
      float* sps = smem + 2048;     // 252
      float* se  = smem + 2304;     // 8*256
      float* ss  = smem + 4352;     // 8*4
      int grp = blk >> 3;
      const float* x2g = x2 + (size_t)grp * (N_*HID_);
      const float* ps2g = ps2 + (size_t)grp * (N_*HEAD_);
      for(int i = tid; i < NA_*HID_; i += 256) sx2[i] = x2g[i];
      for(int i = tid; i < NA_*HEAD_; i += 256) sps[i] = ps2g[i];
      __syncthreads();
      int sg = tid >> 5, l = tid & 31;
      int idx = g0 + sg, j = idx & 63;
      float* orow = hbuf + (size_t)idx * H_;
      if(j == NA_){
        #pragma unroll
        for(int q = 0; q < 4; q++) orow[q*32 + l] = 0.f;
      } else {
        float prj = pr2[(size_t)idx*4 + (l & 3)];
        att_subgroup(sx2, sps, se + sg*256, ss + sg*4, prj, l, orow);
      }
    }
    gbar(bar, (++ep) * NBLK_);
  }

  // ---------------- final Linear(H->D) for rows g0..g0+7 ----------------
  if(tid < 16){
    int r = g0 + (tid >> 1), d = tid & 1;
    const float* hr = hbuf + (size_t)r * H_;
    const float* wr = oW + d * H_;
    float acc = ob[d];
    #pragma unroll 8
    for(int k = 0; k < H_; k++) acc += hr[k]*wr[k];
    pred[r*D_ + d] = acc;
  }
}

extern "C" void kernel_launch(void* const* d_in, const int* in_sizes, int n_in,
                              void* d_out, int out_size, void* d_ws, size_t ws_size,
                              hipStream_t stream){
  const float* inputs = (const float*)d_in[0];
  const float* hidden = (const float*)d_in[1];
  const float* rn1_W1 = (const float*)d_in[4];
  const float* rn1_b1 = (const float*)d_in[5];
  const float* rn1_W2 = (const float*)d_in[6];
  const float* rn1_b2 = (const float*)d_in[7];
  const float* rn2_W1 = (const float*)d_in[8];
  const float* rn2_b1 = (const float*)d_in[9];
  const float* rn2_W2 = (const float*)d_in[10];
  const float* rn2_b2 = (const float*)d_in[11];
  const float* gWih   = (const float*)d_in[12];
  const float* gWhh   = (const float*)d_in[13];
  const float* gbih   = (const float*)d_in[14];
  const float* gbhh   = (const float*)d_in[15];
  const float* oW     = (const float*)d_in[16];
  const float* ob     = (const float*)d_in[17];
  float* ws = (float*)d_ws;

  hipMemsetAsync(ws + OFF_BAR, 0, 64, stream);
  gat1_fc<<<T_*B_, 256, 0, stream>>>(inputs, rn1_W1, rn1_b1, rn1_W2, rn1_b2,
                                     ws + OFF_X1, ws + OFF_PS1, ws + OFF_PR1);
  att8<<<T_*B_*8, 256, 0, stream>>>(ws + OFF_X1, ws + OFF_PS1, ws + OFF_PR1,
                                    ws + OFF_XG);
  loop_k<<<NBLK_, 256, 0, stream>>>(ws + OFF_XG, hidden,
                                    gWih, gWhh, gbih, gbhh,
                                    rn2_W1, rn2_b1, rn2_W2, rn2_b2,
                                    oW, ob,
                                    ws + OFF_H, ws + OFF_X2, ws + OFF_PS2,
                                    ws + OFF_PR2, (float*)d_out,
                                    (unsigned*)(ws + OFF_BAR));
}